// Round 4
// baseline (218.461 us; speedup 1.0000x reference)
//
#include <hip/hip_runtime.h>
#include <cstdint>
#include <cstddef>

#define B_    256
#define D_    2048
#define U_    2048
#define NTOT  8192     // 4*U
#define BN    32       // cols per block
#define BK    128      // k per chunk
#define KSLICE 2048    // K per split (ksplit=2: ks=0 -> W, ks=1 -> U)
#define CHUNKS (KSLICE / BK)   // 16
#define BPITCH 136     // sB pitch in halfs (128 + 8 pad; 272 B, 16B-aligned)

typedef _Float16 half8 __attribute__((ext_vector_type(8)));
typedef float floatx16 __attribute__((ext_vector_type(16)));

// ---------------------------------------------------------------------------
// prep: [x|h] fp32 -> f16, k-octet-major layout [koct = k/8][row][8]: the
// GEMM reads MFMA A-fragments directly from this buffer as aligned 16B
// global loads (512 B contiguous per wave-instr).
// ---------------------------------------------------------------------------
__global__ __launch_bounds__(256) void prep_kernel(
    const float* __restrict__ x, const float* __restrict__ h,
    _Float16* __restrict__ Ahi)
{
    int gid   = blockIdx.x * 256 + threadIdx.x;   // 131072 total
    int koct  = gid >> 8;                         // 0..511
    int row   = gid & 255;
    int col0  = koct * 8;
    const float* src = (col0 < D_) ? (x + row * D_ + col0)
                                   : (h + row * U_ + (col0 - D_));
    float4 v0 = *(const float4*)(src);
    float4 v1 = *(const float4*)(src + 4);
    float v[8] = {v0.x, v0.y, v0.z, v0.w, v1.x, v1.y, v1.z, v1.w};
    half8 hi;
#pragma unroll
    for (int i = 0; i < 8; ++i) hi[i] = (_Float16)v[i];
    *(half8*)(Ahi + (koct * 256 + row) * 8) = hi;
}

// ---------------------------------------------------------------------------
// GEMM: P[ks][m][n0..n0+32) = A(half ks of [x|h]) @ B-cols.
// 512 blocks (2/CU), 256 threads (4 waves), wave-tile 64x32.
// A: per-wave-private rows -> fragments loaded straight from global (L2),
//    fine-grained vmcnt waits, no LDS, no barrier dependence.
// B: double-buffered LDS tile; LOAD_B(kk+1)->regs at chunk top, consumed by
//    cvt+ds_write just before the single per-chunk barrier, so the barrier's
//    vmcnt(0) drain only waits for data needed at that exact point.
// ---------------------------------------------------------------------------
__global__ __launch_bounds__(256) void gemm_kernel(
    const _Float16* __restrict__ Ahi,
    const float* __restrict__ Wz, const float* __restrict__ Wi,
    const float* __restrict__ Wf, const float* __restrict__ Wo,
    const float* __restrict__ Uz, const float* __restrict__ Ui,
    const float* __restrict__ Uf, const float* __restrict__ Uo,
    float* __restrict__ P)
{
    __shared__ __align__(16) _Float16 sB[2][BN * BPITCH];   // 2 x 8.5 KB

    const int t    = threadIdx.x;
    const int w    = t >> 6;          // wave 0..3 (m-group: rows w*64..w*64+63)
    const int lane = t & 63;
    const int lg   = lane >> 5;
    const int lm   = lane & 31;

    const int ntile = blockIdx.x;     // 0..255
    const int ks    = blockIdx.y;     // 0..1
    const int n0    = ntile * BN;
    const int g     = n0 >> 11;       // gate
    const int c0    = n0 & (U_ - 1);
    const int koctB = ks * 256;       // A k-octet base

    const float* wsel[8] = {Wz, Wi, Wf, Wo, Uz, Ui, Uf, Uo};
    const float* Bm   = wsel[ks * 4 + g];
    const float* Bcol = Bm + c0 + lm;     // column base, row stride U_

    const int bko = w * 2 + lg;           // B staging k-octet tasks: bko, bko+8

    floatx16 acc[2] = {};
    float breg[2][8];

#define LOAD_B(kk)                                                            \
    {                                                                         \
        _Pragma("unroll")                                                     \
        for (int j = 0; j < 2; ++j) {                                         \
            const float* src = Bcol + (size_t)((kk) * BK + (bko + 8 * j) * 8) * U_; \
            _Pragma("unroll")                                                 \
            for (int i = 0; i < 8; ++i)                                       \
                breg[j][i] = src[(size_t)i * U_];                             \
        }                                                                     \
    }

#define WRITE_B(buf)                                                          \
    {                                                                         \
        _Pragma("unroll")                                                     \
        for (int j = 0; j < 2; ++j) {                                         \
            half8 hb;                                                         \
            _Pragma("unroll")                                                 \
            for (int i = 0; i < 8; ++i) hb[i] = (_Float16)breg[j][i];         \
            *(half8*)(&sB[buf][lm * BPITCH + (bko + 8 * j) * 8]) = hb;        \
        }                                                                     \
    }

    LOAD_B(0);
    WRITE_B(0);
    __syncthreads();

    const int arow0 = w * 64 + lm;

    for (int kk = 0; kk < CHUNKS; ++kk) {
        int cur = kk & 1;
        if (kk + 1 < CHUNKS) LOAD_B(kk + 1);

        // compute chunk kk: 8 ksteps of 32x32x16, 2 m-tiles
#pragma unroll
        for (int kstep = 0; kstep < 8; ++kstep) {
            int ko = koctB + kk * 16 + kstep * 2 + lg;
            half8 a0 = *(const half8*)(Ahi + ((size_t)ko * 256 + arow0) * 8);
            half8 a1 = *(const half8*)(Ahi + ((size_t)ko * 256 + arow0 + 32) * 8);
            half8 b  = *(const half8*)(&sB[cur][lm * BPITCH + kstep * 16 + lg * 8]);
            acc[0] = __builtin_amdgcn_mfma_f32_32x32x16_f16(a0, b, acc[0], 0, 0, 0);
            acc[1] = __builtin_amdgcn_mfma_f32_32x32x16_f16(a1, b, acc[1], 0, 0, 0);
        }
        if (kk + 1 < CHUNKS) WRITE_B(cur ^ 1);
        __syncthreads();
    }
#undef LOAD_B
#undef WRITE_B

    // C/D layout: col=lane&31, row=(r&3)+8*(r>>2)+4*(lane>>5)
    float* Pks = P + (size_t)ks * ((size_t)B_ * NTOT);
#pragma unroll
    for (int mt = 0; mt < 2; ++mt)
#pragma unroll
        for (int r = 0; r < 16; ++r) {
            int m = w * 64 + mt * 32 + 4 * lg + (r & 3) + 8 * (r >> 2);
            Pks[(size_t)m * NTOT + n0 + lm] = acc[mt][r];
        }
}

// ---------------------------------------------------------------------------
// gates: reduce 2 partials, add bias, sLSTM exponential-gate math,
// out = stack([h_t, c_t, n_t, m_t])
// ---------------------------------------------------------------------------
__global__ __launch_bounds__(256) void gates_kernel(
    const float* __restrict__ P,
    const float* __restrict__ c_prev, const float* __restrict__ n_prev,
    const float* __restrict__ m_prev,
    const float* __restrict__ bz, const float* __restrict__ bi,
    const float* __restrict__ bf, const float* __restrict__ bo,
    float* __restrict__ out)
{
    const size_t PS = (size_t)B_ * NTOT;
    const int OS = B_ * U_;
    int gid = blockIdx.x * 256 + threadIdx.x;   // 131072
    int m = gid >> 9;
    int u = (gid & 511) * 4;

    float pre[4][4];
#pragma unroll
    for (int gi = 0; gi < 4; ++gi) {
        const float* base = P + (size_t)m * NTOT + gi * U_ + u;
        float4 s0 = *(const float4*)(base);
        float4 s1 = *(const float4*)(base + PS);
        pre[gi][0] = s0.x + s1.x;
        pre[gi][1] = s0.y + s1.y;
        pre[gi][2] = s0.z + s1.z;
        pre[gi][3] = s0.w + s1.w;
    }
    float4 bzv = *(const float4*)(bz + u);
    float4 biv = *(const float4*)(bi + u);
    float4 bfv = *(const float4*)(bf + u);
    float4 bov = *(const float4*)(bo + u);
    float bza[4] = {bzv.x, bzv.y, bzv.z, bzv.w};
    float bia[4] = {biv.x, biv.y, biv.z, biv.w};
    float bfa[4] = {bfv.x, bfv.y, bfv.z, bfv.w};
    float boa[4] = {bov.x, bov.y, bov.z, bov.w};

    float4 cp4 = *(const float4*)(c_prev + m * U_ + u);
    float4 np4 = *(const float4*)(n_prev + m * U_ + u);
    float4 mp4 = *(const float4*)(m_prev + m * U_ + u);
    float cpa[4] = {cp4.x, cp4.y, cp4.z, cp4.w};
    float npa[4] = {np4.x, np4.y, np4.z, np4.w};
    float mpa[4] = {mp4.x, mp4.y, mp4.z, mp4.w};

    float hr[4], cr[4], nr[4], mr[4];
#pragma unroll
    for (int e = 0; e < 4; ++e) {
        float zt = pre[0][e] + bza[e];
        float it = pre[1][e] + bia[e];
        float ft = pre[2][e] + bfa[e];
        float ot = pre[3][e] + boa[e];
        float mp = mpa[e];
        float m_t = fmaxf(it + mp, it);
        float i_t = expf(it - m_t);
        float f_t = expf(ft + mp - m_t);
        float o_t = 1.0f / (1.0f + expf(-ot));
        float z_t = tanhf(zt);
        float c_t = f_t * cpa[e] + i_t * z_t;
        float n_t = f_t * npa[e] + i_t;
        float h_t = o_t * (c_t / (n_t + 1e-8f));
        hr[e] = h_t; cr[e] = c_t; nr[e] = n_t; mr[e] = m_t;
    }
    float4 hv = {hr[0], hr[1], hr[2], hr[3]};
    float4 cv = {cr[0], cr[1], cr[2], cr[3]};
    float4 nv = {nr[0], nr[1], nr[2], nr[3]};
    float4 mv = {mr[0], mr[1], mr[2], mr[3]};
    *(float4*)(out + 0 * OS + m * U_ + u) = hv;
    *(float4*)(out + 1 * OS + m * U_ + u) = cv;
    *(float4*)(out + 2 * OS + m * U_ + u) = nv;
    *(float4*)(out + 3 * OS + m * U_ + u) = mv;
}

extern "C" void kernel_launch(void* const* d_in, const int* in_sizes, int n_in,
                              void* d_out, int out_size, void* d_ws, size_t ws_size,
                              hipStream_t stream)
{
    const float* x  = (const float*)d_in[0];
    const float* h  = (const float*)d_in[1];
    const float* cp = (const float*)d_in[2];
    const float* np = (const float*)d_in[3];
    const float* mp = (const float*)d_in[4];
    const float* Wz = (const float*)d_in[5];
    const float* Wi = (const float*)d_in[6];
    const float* Wf = (const float*)d_in[7];
    const float* Wo = (const float*)d_in[8];
    const float* bz = (const float*)d_in[9];
    const float* bi = (const float*)d_in[10];
    const float* bf = (const float*)d_in[11];
    const float* bo = (const float*)d_in[12];
    const float* Uz = (const float*)d_in[13];
    const float* Ui = (const float*)d_in[14];
    const float* Uf = (const float*)d_in[15];
    const float* Uo = (const float*)d_in[16];

    float* P = (float*)d_ws;   // 2*256*8192 f32 = 16.8 MB
    _Float16* Ahi = (_Float16*)((char*)d_ws + (size_t)2 * B_ * NTOT * sizeof(float));

    prep_kernel<<<512, 256, 0, stream>>>(x, h, Ahi);
    gemm_kernel<<<dim3(256, 2), 256, 0, stream>>>(Ahi,
        Wz, Wi, Wf, Wo, Uz, Ui, Uf, Uo, P);
    gates_kernel<<<512, 256, 0, stream>>>(P, cp, np, mp, bz, bi, bf, bo,
        (float*)d_out);
}

// Round 5
// 217.957 us; speedup vs baseline: 1.0023x; 1.0023x over previous
//
#include <hip/hip_runtime.h>
#include <cstdint>
#include <cstddef>

#define B_     256
#define D_     2048
#define U_     2048
#define NTOT   8192    // 4*U
#define BN     128     // cols per block
#define BK     64      // k per chunk
#define KS     4       // k-splits
#define KSLICE 1024    // K per split
#define CHUNKS (KSLICE / BK)   // 16
#define BPITCH 72      // sB pitch in halfs (64 + 8; 144 B, 16B-aligned)

typedef _Float16 half8 __attribute__((ext_vector_type(8)));
typedef float floatx16 __attribute__((ext_vector_type(16)));

// ---------------------------------------------------------------------------
// prep: [x|h] fp32 -> f16, k-octet-major [koct = k/8][row][8]: GEMM stages A
// with contiguous global_load_lds dwordx4 and reads fragments as ds_read_b128.
// ---------------------------------------------------------------------------
__global__ __launch_bounds__(256) void prep_kernel(
    const float* __restrict__ x, const float* __restrict__ h,
    _Float16* __restrict__ Ahi)
{
    int gid   = blockIdx.x * 256 + threadIdx.x;   // 131072 total
    int koct  = gid >> 8;                         // 0..511
    int row   = gid & 255;
    int col0  = koct * 8;
    const float* src = (col0 < D_) ? (x + row * D_ + col0)
                                   : (h + row * U_ + (col0 - D_));
    float4 v0 = *(const float4*)(src);
    float4 v1 = *(const float4*)(src + 4);
    float v[8] = {v0.x, v0.y, v0.z, v0.w, v1.x, v1.y, v1.z, v1.w};
    half8 hi;
#pragma unroll
    for (int i = 0; i < 8; ++i) hi[i] = (_Float16)v[i];
    *(half8*)(Ahi + (koct * 256 + row) * 8) = hi;
}

// ---------------------------------------------------------------------------
// GEMM: P[ks][m][n0..n0+128) = A(k-slice ks) @ B-cols.  256 blocks (1/CU),
// 256 threads (4 waves), wave-tile 64x128 (acc 2x4 -> 128 VGPRs, forcing
// real ILP).  A double-buffered via global_load_lds DMA (no VGPR, deep
// queue).  B double-buffered via reg->cvt->ds_write transpose; B loads for
// k+1 issued at chunk top.  vmcnt is in-order and A-DMA (L2-fast) precedes
// B (HBM-slow), so WRITE_B's wait and the barrier cost no extra drain.
// ---------------------------------------------------------------------------
__global__ __launch_bounds__(256) void gemm_kernel(
    const _Float16* __restrict__ Ahi,
    const float* __restrict__ Wz, const float* __restrict__ Wi,
    const float* __restrict__ Wf, const float* __restrict__ Wo,
    const float* __restrict__ Uz, const float* __restrict__ Ui,
    const float* __restrict__ Uf, const float* __restrict__ Uo,
    float* __restrict__ P)
{
    __shared__ __align__(16) _Float16 sA[2][8 * 256 * 8];   // 2 x 32 KB
    __shared__ __align__(16) _Float16 sB[2][BN * BPITCH];   // 2 x 18 KB

    const int t    = threadIdx.x;
    const int w    = t >> 6;          // wave 0..3 (rows w*64..w*64+63)
    const int lane = t & 63;
    const int lg   = lane >> 5;
    const int lm   = lane & 31;

    const int ntile = blockIdx.x;     // 0..63
    const int ks    = blockIdx.y;     // 0..3
    const int n0    = ntile * BN;
    const int g     = n0 >> 11;       // gate
    const int c0    = n0 & (U_ - 1);
    const int krow0 = (ks & 1) * KSLICE;
    const int koctB = ks * 128;       // A k-octet base

    const float* wsel[8] = {Wz, Wi, Wf, Wo, Uz, Ui, Uf, Uo};
    const float* Bm = wsel[(ks >> 1) * 4 + g];

    // B staging: col = (w&1)*64 + lane; k-octets ko = (w>>1) + 2j, j=0..3
    const int colT = (w & 1) * 64 + lane;
    const int koT  = w >> 1;
    const float* Bcol = Bm + (size_t)krow0 * U_ + c0 + colT;

    floatx16 acc[2][4] = {};
    float breg[4][8];

#define ISSUE_A(kk, buf)                                                      \
    {                                                                         \
        _Pragma("unroll")                                                     \
        for (int j = 0; j < 8; ++j) {                                         \
            int idx  = j * 256 + t;                                           \
            size_t gidx = ((size_t)(koctB + (kk) * 8) * 256 + idx) * 8;       \
            __builtin_amdgcn_global_load_lds(                                 \
                (const __attribute__((address_space(1))) void*)(Ahi + gidx),  \
                (__attribute__((address_space(3))) void*)(&sA[buf][idx * 8]), \
                16, 0, 0);                                                    \
        }                                                                     \
    }

#define LOAD_B(kk)                                                            \
    {                                                                         \
        _Pragma("unroll")                                                     \
        for (int j = 0; j < 4; ++j) {                                         \
            const float* src = Bcol + (size_t)((kk) * BK + (koT + 2 * j) * 8) * U_; \
            _Pragma("unroll")                                                 \
            for (int i = 0; i < 8; ++i)                                       \
                breg[j][i] = src[(size_t)i * U_];                             \
        }                                                                     \
    }

#define WRITE_B(buf)                                                          \
    {                                                                         \
        _Pragma("unroll")                                                     \
        for (int j = 0; j < 4; ++j) {                                         \
            half8 hb;                                                         \
            _Pragma("unroll")                                                 \
            for (int i = 0; i < 8; ++i) hb[i] = (_Float16)breg[j][i];         \
            *(half8*)(&sB[buf][colT * BPITCH + (koT + 2 * j) * 8]) = hb;      \
        }                                                                     \
    }

    ISSUE_A(0, 0);
    LOAD_B(0);
    WRITE_B(0);
    __syncthreads();

    for (int kk = 0; kk < CHUNKS; ++kk) {
        int cur = kk & 1;
        if (kk + 1 < CHUNKS) {
            ISSUE_A(kk + 1, cur ^ 1);
            LOAD_B(kk + 1);
        }
        // compute chunk kk: 4 ksteps of 32x32x16, 2 m-tiles x 4 n-tiles
#pragma unroll
        for (int kstep = 0; kstep < 4; ++kstep) {
            half8 a[2], b[4];
#pragma unroll
            for (int mt = 0; mt < 2; ++mt) {
                int row = w * 64 + mt * 32 + lm;
                a[mt] = *(const half8*)(&sA[cur][((kstep * 2 + lg) * 256 + row) * 8]);
            }
#pragma unroll
            for (int nt = 0; nt < 4; ++nt) {
                int col = nt * 32 + lm;
                b[nt] = *(const half8*)(&sB[cur][col * BPITCH + kstep * 16 + lg * 8]);
            }
#pragma unroll
            for (int mt = 0; mt < 2; ++mt)
#pragma unroll
                for (int nt = 0; nt < 4; ++nt)
                    acc[mt][nt] = __builtin_amdgcn_mfma_f32_32x32x16_f16(
                        a[mt], b[nt], acc[mt][nt], 0, 0, 0);
        }
        if (kk + 1 < CHUNKS) WRITE_B(cur ^ 1);
        __syncthreads();
    }
#undef ISSUE_A
#undef LOAD_B
#undef WRITE_B

    // C/D layout: col=lane&31, row=(r&3)+8*(r>>2)+4*(lane>>5)
    float* Pks = P + (size_t)ks * ((size_t)B_ * NTOT);
#pragma unroll
    for (int mt = 0; mt < 2; ++mt)
#pragma unroll
        for (int nt = 0; nt < 4; ++nt) {
            int n = n0 + nt * 32 + lm;
#pragma unroll
            for (int r = 0; r < 16; ++r) {
                int m = w * 64 + mt * 32 + 4 * lg + (r & 3) + 8 * (r >> 2);
                Pks[(size_t)m * NTOT + n] = acc[mt][nt][r];
            }
        }
}

// ---------------------------------------------------------------------------
// gates: reduce 4 partials, add bias, sLSTM exponential-gate math,
// out = stack([h_t, c_t, n_t, m_t])
// ---------------------------------------------------------------------------
__global__ __launch_bounds__(256) void gates_kernel(
    const float* __restrict__ P,
    const float* __restrict__ c_prev, const float* __restrict__ n_prev,
    const float* __restrict__ m_prev,
    const float* __restrict__ bz, const float* __restrict__ bi,
    const float* __restrict__ bf, const float* __restrict__ bo,
    float* __restrict__ out)
{
    const size_t PS = (size_t)B_ * NTOT;
    const int OS = B_ * U_;
    int gid = blockIdx.x * 256 + threadIdx.x;   // 131072
    int m = gid >> 9;
    int u = (gid & 511) * 4;

    float pre[4][4];
#pragma unroll
    for (int gi = 0; gi < 4; ++gi) {
        const float* base = P + (size_t)m * NTOT + gi * U_ + u;
        float4 s0 = *(const float4*)(base);
        float4 s1 = *(const float4*)(base + PS);
        float4 s2 = *(const float4*)(base + 2 * PS);
        float4 s3 = *(const float4*)(base + 3 * PS);
        pre[gi][0] = s0.x + s1.x + s2.x + s3.x;
        pre[gi][1] = s0.y + s1.y + s2.y + s3.y;
        pre[gi][2] = s0.z + s1.z + s2.z + s3.z;
        pre[gi][3] = s0.w + s1.w + s2.w + s3.w;
    }
    float4 bzv = *(const float4*)(bz + u);
    float4 biv = *(const float4*)(bi + u);
    float4 bfv = *(const float4*)(bf + u);
    float4 bov = *(const float4*)(bo + u);
    float bza[4] = {bzv.x, bzv.y, bzv.z, bzv.w};
    float bia[4] = {biv.x, biv.y, biv.z, biv.w};
    float bfa[4] = {bfv.x, bfv.y, bfv.z, bfv.w};
    float boa[4] = {bov.x, bov.y, bov.z, bov.w};

    float4 cp4 = *(const float4*)(c_prev + m * U_ + u);
    float4 np4 = *(const float4*)(n_prev + m * U_ + u);
    float4 mp4 = *(const float4*)(m_prev + m * U_ + u);
    float cpa[4] = {cp4.x, cp4.y, cp4.z, cp4.w};
    float npa[4] = {np4.x, np4.y, np4.z, np4.w};
    float mpa[4] = {mp4.x, mp4.y, mp4.z, mp4.w};

    float hr[4], cr[4], nr[4], mr[4];
#pragma unroll
    for (int e = 0; e < 4; ++e) {
        float zt = pre[0][e] + bza[e];
        float it = pre[1][e] + bia[e];
        float ft = pre[2][e] + bfa[e];
        float ot = pre[3][e] + boa[e];
        float mp = mpa[e];
        float m_t = fmaxf(it + mp, it);
        float i_t = expf(it - m_t);
        float f_t = expf(ft + mp - m_t);
        float o_t = 1.0f / (1.0f + expf(-ot));
        float z_t = tanhf(zt);
        float c_t = f_t * cpa[e] + i_t * z_t;
        float n_t = f_t * npa[e] + i_t;
        float h_t = o_t * (c_t / (n_t + 1e-8f));
        hr[e] = h_t; cr[e] = c_t; nr[e] = n_t; mr[e] = m_t;
    }
    float4 hv = {hr[0], hr[1], hr[2], hr[3]};
    float4 cv = {cr[0], cr[1], cr[2], cr[3]};
    float4 nv = {nr[0], nr[1], nr[2], nr[3]};
    float4 mv = {mr[0], mr[1], mr[2], mr[3]};
    *(float4*)(out + 0 * OS + m * U_ + u) = hv;
    *(float4*)(out + 1 * OS + m * U_ + u) = cv;
    *(float4*)(out + 2 * OS + m * U_ + u) = nv;
    *(float4*)(out + 3 * OS + m * U_ + u) = mv;
}

extern "C" void kernel_launch(void* const* d_in, const int* in_sizes, int n_in,
                              void* d_out, int out_size, void* d_ws, size_t ws_size,
                              hipStream_t stream)
{
    const float* x  = (const float*)d_in[0];
    const float* h  = (const float*)d_in[1];
    const float* cp = (const float*)d_in[2];
    const float* np = (const float*)d_in[3];
    const float* mp = (const float*)d_in[4];
    const float* Wz = (const float*)d_in[5];
    const float* Wi = (const float*)d_in[6];
    const float* Wf = (const float*)d_in[7];
    const float* Wo = (const float*)d_in[8];
    const float* bz = (const float*)d_in[9];
    const float* bi = (const float*)d_in[10];
    const float* bf = (const float*)d_in[11];
    const float* bo = (const float*)d_in[12];
    const float* Uz = (const float*)d_in[13];
    const float* Ui = (const float*)d_in[14];
    const float* Uf = (const float*)d_in[15];
    const float* Uo = (const float*)d_in[16];

    float* P = (float*)d_ws;   // 4*256*8192 f32 = 33.55 MB
    _Float16* Ahi = (_Float16*)((char*)d_ws + (size_t)4 * B_ * NTOT * sizeof(float));

    prep_kernel<<<512, 256, 0, stream>>>(x, h, Ahi);
    gemm_kernel<<<dim3(64, 4), 256, 0, stream>>>(Ahi,
        Wz, Wi, Wf, Wo, Uz, Ui, Uf, Uo, P);
    gates_kernel<<<512, 256, 0, stream>>>(P, cp, np, mp, bz, bi, bf, bo,
        (float*)d_out);
}